// Round 3
// baseline (302.006 us; speedup 1.0000x reference)
//
#include <hip/hip_runtime.h>

#define D 128
#define ROWS 64   // nodes per fused block

// ---------------------------------------------------------------------------
// CSR build phase 1: histogram of dst
// ---------------------------------------------------------------------------
__global__ __launch_bounds__(256) void hist_k(
    const int* __restrict__ edst, int* __restrict__ cnt, int E)
{
    int i = blockIdx.x * 256 + threadIdx.x;
    if (i < E) atomicAdd(&cnt[edst[i]], 1);
}

// ---------------------------------------------------------------------------
// CSR build phase 2: bucket base allocation (wave scan + one ticket atomic).
// ---------------------------------------------------------------------------
__global__ __launch_bounds__(256) void alloc_k(
    const int* __restrict__ cnt, int* __restrict__ ticket,
    int* __restrict__ rbase, int* __restrict__ fbase, int N)
{
    int n = blockIdx.x * 256 + threadIdx.x;
    int lane = threadIdx.x & 63;
    int c = (n < N) ? cnt[n] : 0;

    int inc = c;
#pragma unroll
    for (int off = 1; off < 64; off <<= 1) {
        int up = __shfl_up(inc, off, 64);
        if (lane >= off) inc += up;
    }
    int wave_total = __shfl(inc, 63, 64);
    int wave_base = 0;
    if (lane == 63) wave_base = atomicAdd(ticket, wave_total);
    wave_base = __shfl(wave_base, 63, 64);
    int base = wave_base + inc - c;

    if (n < N) {
        rbase[n] = base;
        fbase[n] = base;
    }
}

// ---------------------------------------------------------------------------
// CSR build phase 3: scatter edges into buckets, packed (src, e_bits).
// ---------------------------------------------------------------------------
__global__ __launch_bounds__(256) void fill_k(
    const int* __restrict__ esrc, const int* __restrict__ edst,
    const float* __restrict__ ee, int* __restrict__ fbase,
    int2* __restrict__ perm, int E)
{
    int i = blockIdx.x * 256 + threadIdx.x;
    if (i >= E) return;
    int d = edst[i];
    int slot = atomicAdd(&fbase[d], 1);
    perm[slot] = make_int2(esrc[i], __float_as_int(ee[i]));
}

// ---------------------------------------------------------------------------
// Fused aggregation + GEMM + epilogue.
// Phase A: one wave per node (16 nodes/wave), gather e*feat[src] into LDS Ash.
// Phase B: K-tiled register GEMM out of Ash/Wl; epilogue mean+relu+residual.
// ---------------------------------------------------------------------------
__global__ __launch_bounds__(256) void fused_k(
    const float* __restrict__ feat,
    const int2* __restrict__ perm,
    const int* __restrict__ rbase,
    const int* __restrict__ cnt,
    const float* __restrict__ alpha,
    const float* __restrict__ W,     // [D*D] row-major W[j][k]
    const float* __restrict__ b,
    float* __restrict__ out,
    int N)
{
    __shared__ float Ash[ROWS * D];   // 32 KB: aggregated rows
    __shared__ float Wl[D * 36];      // 18.4 KB: W K-tile, padded stride
    __shared__ float esum_sh[ROWS];
    __shared__ float deg_sh[ROWS];
    __shared__ float b_sh[D];

    const int tid = threadIdx.x;
    const int wave = tid >> 6;
    const int lane = tid & 63;
    const int nbase = blockIdx.x * ROWS;

    if (tid < 32) ((float4*)b_sh)[tid] = ((const float4*)b)[tid];

    // ---- Phase A: aggregate 16 nodes per wave ----
#pragma unroll 1
    for (int i = 0; i < 16; ++i) {
        int r = wave * 16 + i;
        int node = nbase + r;
        if (node < N) {
            int base = rbase[node];
            int c = cnt[node];
            float2 acc = make_float2(0.f, 0.f);
            float es = 0.f;
            int j = 0;
            for (; j + 4 <= c; j += 4) {
                int2 p0 = perm[base + j + 0];
                int2 p1 = perm[base + j + 1];
                int2 p2 = perm[base + j + 2];
                int2 p3 = perm[base + j + 3];
                float2 v0 = ((const float2*)(feat + (size_t)p0.x * D))[lane];
                float2 v1 = ((const float2*)(feat + (size_t)p1.x * D))[lane];
                float2 v2 = ((const float2*)(feat + (size_t)p2.x * D))[lane];
                float2 v3 = ((const float2*)(feat + (size_t)p3.x * D))[lane];
                float e0 = __int_as_float(p0.y), e1 = __int_as_float(p1.y);
                float e2 = __int_as_float(p2.y), e3 = __int_as_float(p3.y);
                acc.x += e0 * v0.x; acc.y += e0 * v0.y;
                acc.x += e1 * v1.x; acc.y += e1 * v1.y;
                acc.x += e2 * v2.x; acc.y += e2 * v2.y;
                acc.x += e3 * v3.x; acc.y += e3 * v3.y;
                es += e0 + e1 + e2 + e3;
            }
            for (; j < c; ++j) {
                int2 p = perm[base + j];
                float e = __int_as_float(p.y);
                float2 v = ((const float2*)(feat + (size_t)p.x * D))[lane];
                acc.x += e * v.x; acc.y += e * v.y;
                es += e;
            }
            ((float2*)(Ash + r * D))[lane] = acc;
            if (lane == 0) { esum_sh[r] = es; deg_sh[r] = (float)c; }
        }
    }

    // ---- Phase B: GEMM Ash @ W^T ----
    const int j32 = tid & 31;
    const int rg = tid >> 5;

    float acc[8][4];
#pragma unroll
    for (int i = 0; i < 8; ++i)
#pragma unroll
        for (int m = 0; m < 4; ++m) acc[i][m] = 0.0f;

    for (int kt = 0; kt < 4; ++kt) {
        // stage W chunk: rows j=0..127, k = kt*32 .. kt*32+31
#pragma unroll
        for (int q = 0; q < 4; ++q) {
            int idx = q * 256 + tid;
            int jj = idx >> 3;
            int c4 = idx & 7;
            float4 v = *(const float4*)&W[(size_t)jj * D + kt * 32 + c4 * 4];
            *(float4*)&Wl[jj * 36 + c4 * 4] = v;
        }
        __syncthreads();   // Wl ready; also (kt==0) Ash/esum/b_sh ready

#pragma unroll
        for (int k0 = 0; k0 < 32; k0 += 4) {
            float4 wv[4];
#pragma unroll
            for (int m = 0; m < 4; ++m)
                wv[m] = *(const float4*)&Wl[(j32 + 32 * m) * 36 + k0];
#pragma unroll
            for (int i = 0; i < 8; ++i) {
                int r = rg * 8 + i;
                float4 av = *(const float4*)&Ash[r * D + kt * 32 + k0];
#pragma unroll
                for (int m = 0; m < 4; ++m) {
                    acc[i][m] += av.x * wv[m].x;
                    acc[i][m] += av.y * wv[m].y;
                    acc[i][m] += av.z * wv[m].z;
                    acc[i][m] += av.w * wv[m].w;
                }
            }
        }
        __syncthreads();   // done with Wl before next kt overwrites
    }

    // ---- Epilogue ----
#pragma unroll
    for (int i = 0; i < 8; ++i) {
        int r = rg * 8 + i;
        int n = nbase + r;
        if (n >= N) continue;
        float es = esum_sh[r];
        float inv = 1.0f / fmaxf(deg_sh[r], 1.0f);
        float al = alpha[n];
#pragma unroll
        for (int m = 0; m < 4; ++m) {
            int c = j32 + 32 * m;
            float v = (acc[i][m] + es * b_sh[c]) * inv;
            v = fmaxf(v, 0.0f);
            out[(size_t)n * D + c] = v + al * feat[(size_t)n * D + c];
        }
    }
}

extern "C" void kernel_launch(void* const* d_in, const int* in_sizes, int n_in,
                              void* d_out, int out_size, void* d_ws, size_t ws_size,
                              hipStream_t stream) {
    const float* feat  = (const float*)d_in[0];
    const float* alpha = (const float*)d_in[1];
    const int*   esrc  = (const int*)d_in[2];
    const int*   edst  = (const int*)d_in[3];
    const float* ee    = (const float*)d_in[4];
    const float* W     = (const float*)d_in[5];
    const float* b     = (const float*)d_in[6];
    float* out = (float*)d_out;

    const int E = in_sizes[2];
    const int N = in_sizes[0] / D;

    // workspace layout
    int2*  perm   = (int2*)d_ws;              // E entries
    int*   cnt    = (int*)(perm + E);         // N
    int*   ticket = cnt + N;                  // 1
    int*   rbase  = ticket + 1;               // N
    int*   fbase  = rbase + N;                // N

    hipMemsetAsync(cnt, 0, (size_t)(N + 1) * sizeof(int), stream);

    int eblocks = (E + 255) / 256;
    int nblocks = (N + 255) / 256;

    hist_k<<<eblocks, 256, 0, stream>>>(edst, cnt, E);
    alloc_k<<<nblocks, 256, 0, stream>>>(cnt, ticket, rbase, fbase, N);
    fill_k<<<eblocks, 256, 0, stream>>>(esrc, edst, ee, fbase, perm, E);

    int fblocks = (N + ROWS - 1) / ROWS;
    fused_k<<<fblocks, 256, 0, stream>>>(feat, perm, rbase, cnt, alpha, W, b, out, N);
}